// Round 1
// baseline (211.560 us; speedup 1.0000x reference)
//
#include <hip/hip_runtime.h>
#include <math.h>

namespace {

constexpr int Bc   = 16;    // batch
constexpr int Hc   = 16;    // heads
constexpr int Dc   = 128;   // head dim (K/Q)
constexpr int LVc  = 128;   // head dim (V)
constexpr int SPLc = 4;     // kv splits
constexpr float LOGIT_CAP = 30.0f;

// One block per (b, h, s). 256 threads = 8 groups x 32 lanes.
// Each group streams tokens l = g, g+8, ... ; lanes cover the 128-dim row
// as float4 (coalesced 512 B per group-load).
__launch_bounds__(256, 4)
__global__ void decode_attn(const float* __restrict__ q,
                            const float* __restrict__ kbuf,
                            const float* __restrict__ vbuf,
                            const int*   __restrict__ indptr,
                            const int*   __restrict__ indices,
                            const int*   __restrict__ nsplits,
                            float*       __restrict__ out)
{
    const int bid = blockIdx.x;             // b*H*S + h*S + s
    const int s   = bid & (SPLc - 1);
    const int h   = (bid >> 2) & (Hc - 1);
    const int b   = bid >> 6;

    const int tid  = threadIdx.x;
    const int g    = tid >> 5;              // group 0..7
    const int lane = tid & 31;              // lane within group

    const int kv_start = indptr[b];
    const int kv_len   = indptr[b + 1] - kv_start;
    const int ns       = nsplits[b];
    const int Ls       = kv_len / ns;       // tokens in this split (1024)
    const int tok0     = kv_start + s * Ls;

    __shared__ int   s_idx[1024];
    __shared__ float s_p[1024];
    __shared__ float s_wred[4];
    __shared__ float s_wred2[4];

    // stage gathered indices (coalesced)
    for (int i = tid; i < Ls; i += 256)
        s_idx[i] = indices[tok0 + i];

    // q fragment held in registers (loop-invariant)
    const float4 q4 = *reinterpret_cast<const float4*>(
        q + ((size_t)b * Hc + h) * Dc + 4 * lane);

    __syncthreads();

    constexpr float SM_SCALE = 0.08838834764831845f;  // 1/sqrt(128)
    constexpr float INV_CAP  = SM_SCALE / LOGIT_CAP;

    // ---------------- QK^T + logit cap ----------------
    #pragma unroll 4
    for (int l = g; l < Ls; l += 8) {
        const int idx = s_idx[l];
        const float4 k4 = *reinterpret_cast<const float4*>(
            kbuf + ((size_t)idx * Hc + h) * Dc + 4 * lane);
        float part = q4.x * k4.x + q4.y * k4.y + q4.z * k4.z + q4.w * k4.w;
        // reduce across the 32-lane group (xor<=16 never crosses groups)
        part += __shfl_xor(part, 16);
        part += __shfl_xor(part, 8);
        part += __shfl_xor(part, 4);
        part += __shfl_xor(part, 2);
        part += __shfl_xor(part, 1);
        const float logit = LOGIT_CAP * tanhf(part * INV_CAP);  // all lanes, no divergence
        if (lane == 0) s_p[l] = logit;
    }
    __syncthreads();

    // ---------------- split max ----------------
    float lm = -INFINITY;
    for (int i = tid; i < Ls; i += 256) lm = fmaxf(lm, s_p[i]);
    #pragma unroll
    for (int off = 32; off >= 1; off >>= 1) lm = fmaxf(lm, __shfl_xor(lm, off));
    if ((tid & 63) == 0) s_wred[tid >> 6] = lm;
    __syncthreads();
    const float m = fmaxf(fmaxf(s_wred[0], s_wred[1]), fmaxf(s_wred[2], s_wred[3]));

    // ---------------- exp + running sum ----------------
    float lsum = 0.f;
    for (int i = tid; i < Ls; i += 256) {   // same element partition as max loop -> no race
        const float p = __expf(s_p[i] - m);
        s_p[i] = p;
        lsum += p;
    }
    #pragma unroll
    for (int off = 32; off >= 1; off >>= 1) lsum += __shfl_xor(lsum, off);
    if ((tid & 63) == 0) s_wred2[tid >> 6] = lsum;
    __syncthreads();
    const float esum = (s_wred2[0] + s_wred2[1]) + (s_wred2[2] + s_wred2[3]);

    // ---------------- P @ V ----------------
    float4 acc = make_float4(0.f, 0.f, 0.f, 0.f);
    #pragma unroll 4
    for (int l = g; l < Ls; l += 8) {
        const int idx = s_idx[l];
        const float p = s_p[l];             // LDS broadcast
        const float4 v4 = *reinterpret_cast<const float4*>(
            vbuf + ((size_t)idx * Hc + h) * LVc + 4 * lane);
        acc.x += p * v4.x;
        acc.y += p * v4.y;
        acc.z += p * v4.z;
        acc.w += p * v4.w;
    }
    __syncthreads();                        // all s_p reads done; reuse as [8][128] acc
    float* s_acc = s_p;
    *reinterpret_cast<float4*>(&s_acc[g * 128 + 4 * lane]) = acc;
    __syncthreads();
    #pragma unroll
    for (int off = 4; off >= 1; off >>= 1) {
        if (g < off) {
            float4 a = *reinterpret_cast<float4*>(&s_acc[g * 128 + 4 * lane]);
            const float4 c = *reinterpret_cast<const float4*>(&s_acc[(g + off) * 128 + 4 * lane]);
            a.x += c.x; a.y += c.y; a.z += c.z; a.w += c.w;
            *reinterpret_cast<float4*>(&s_acc[g * 128 + 4 * lane]) = a;
        }
        __syncthreads();
    }

    // ---------------- epilogue ----------------
    if (g == 0) {
        float4 r = *reinterpret_cast<const float4*>(&s_acc[4 * lane]);
        const float inv = 1.0f / esum;
        r.x *= inv; r.y *= inv; r.z *= inv; r.w *= inv;
        float* outp = out + (((size_t)b * Hc + h) * SPLc + s) * LVc + 4 * lane;
        *reinterpret_cast<float4*>(outp) = r;
        if (lane == 0) {
            out[(size_t)Bc * Hc * SPLc * LVc + ((size_t)b * Hc + h) * SPLc + s] =
                m + logf(esum);
        }
    }
}

} // anonymous namespace

extern "C" void kernel_launch(void* const* d_in, const int* in_sizes, int n_in,
                              void* d_out, int out_size, void* d_ws, size_t ws_size,
                              hipStream_t stream) {
    const float* q       = (const float*)d_in[0];
    const float* kbuf    = (const float*)d_in[1];
    const float* vbuf    = (const float*)d_in[2];
    const int*   indptr  = (const int*)d_in[3];
    const int*   indices = (const int*)d_in[4];
    const int*   nspl    = (const int*)d_in[5];
    float* outp = (float*)d_out;

    dim3 grid(Bc * Hc * SPLc);   // 1024 blocks: one per (b, h, split)
    dim3 block(256);
    hipLaunchKernelGGL(decode_attn, grid, block, 0, stream,
                       q, kbuf, vbuf, indptr, indices, nspl, outp);
}

// Round 2
// 189.535 us; speedup vs baseline: 1.1162x; 1.1162x over previous
//
#include <hip/hip_runtime.h>
#include <math.h>

namespace {

constexpr int Bc   = 16;    // batch
constexpr int Hc   = 16;    // heads
constexpr int Dc   = 128;   // head dim (K/Q)
constexpr int LVc  = 128;   // head dim (V)
constexpr int SPLc = 4;     // kv splits
constexpr float LOGIT_CAP = 30.0f;

// One block per (b, h, s). 256 threads = 8 groups x 32 lanes.
// Single streaming pass: logits are capped at +/-30 by tanh, so m=30 is a
// valid (algebraically invariant) softmax shift -> no max pass needed.
// Each group-iteration keeps 1 KB (K row + V row) in flight; no barriers
// until the final 8-way merge.
__launch_bounds__(256, 4)
__global__ void decode_attn(const float* __restrict__ q,
                            const float* __restrict__ kbuf,
                            const float* __restrict__ vbuf,
                            const int*   __restrict__ indptr,
                            const int*   __restrict__ indices,
                            const int*   __restrict__ nsplits,
                            float*       __restrict__ out)
{
    const int bid = blockIdx.x;             // b*H*S + h*S + s
    const int s   = bid & (SPLc - 1);
    const int h   = (bid >> 2) & (Hc - 1);
    const int b   = bid >> 6;

    const int tid  = threadIdx.x;
    const int g    = tid >> 5;              // group 0..7
    const int lane = tid & 31;              // lane within group

    const int kv_start = indptr[b];
    const int kv_len   = indptr[b + 1] - kv_start;
    const int ns       = nsplits[b];
    const int Ls       = kv_len / ns;       // tokens in this split (1024)
    const int tok0     = kv_start + s * Ls;

    __shared__ int   s_idx[1024];
    __shared__ float s_merge[8 * 128];
    __shared__ float s_esum[8];

    // stage gathered indices (coalesced)
    for (int i = tid; i < Ls; i += 256)
        s_idx[i] = indices[tok0 + i];

    // q fragment in registers (loop-invariant)
    const float4 q4 = *reinterpret_cast<const float4*>(
        q + ((size_t)b * Hc + h) * Dc + 4 * lane);

    __syncthreads();

    constexpr float SM_SCALE = 0.08838834764831845f;  // 1/sqrt(128)
    constexpr float INV_CAP  = SM_SCALE / LOGIT_CAP;
    constexpr float M_FIX    = LOGIT_CAP;              // logits <= 30 always

    float4 acc = make_float4(0.f, 0.f, 0.f, 0.f);
    float  esum = 0.f;                      // uniform across the 32-lane group

    #pragma unroll 4
    for (int l = g; l < Ls; l += 8) {
        const int idx = s_idx[l];
        const size_t row = ((size_t)idx * Hc + h);
        const float4 k4 = *reinterpret_cast<const float4*>(kbuf + row * Dc  + 4 * lane);
        const float4 v4 = *reinterpret_cast<const float4*>(vbuf + row * LVc + 4 * lane);

        float part = q4.x * k4.x + q4.y * k4.y + q4.z * k4.z + q4.w * k4.w;
        part += __shfl_xor(part, 16);       // xor<=16 stays inside the 32-lane group
        part += __shfl_xor(part, 8);
        part += __shfl_xor(part, 4);
        part += __shfl_xor(part, 2);
        part += __shfl_xor(part, 1);

        const float logit = LOGIT_CAP * tanhf(part * INV_CAP);
        const float p = __expf(logit - M_FIX);   // in [e^-60, 1], always normal
        esum += p;                               // each token counted once per lane
        acc.x += p * v4.x;
        acc.y += p * v4.y;
        acc.z += p * v4.z;
        acc.w += p * v4.w;
    }

    // ---------------- 8-way group merge ----------------
    *reinterpret_cast<float4*>(&s_merge[g * 128 + 4 * lane]) = acc;
    if (lane == 0) s_esum[g] = esum;
    __syncthreads();

    #pragma unroll
    for (int off = 4; off >= 1; off >>= 1) {
        if (g < off) {
            float4 a = *reinterpret_cast<float4*>(&s_merge[g * 128 + 4 * lane]);
            const float4 c = *reinterpret_cast<const float4*>(&s_merge[(g + off) * 128 + 4 * lane]);
            a.x += c.x; a.y += c.y; a.z += c.z; a.w += c.w;
            *reinterpret_cast<float4*>(&s_merge[g * 128 + 4 * lane]) = a;
            if (lane == 0) s_esum[g] += s_esum[g + off];
        }
        __syncthreads();
    }

    // ---------------- epilogue ----------------
    if (g == 0) {
        const float es  = s_esum[0];
        const float inv = 1.0f / es;
        float4 r = *reinterpret_cast<const float4*>(&s_merge[4 * lane]);
        r.x *= inv; r.y *= inv; r.z *= inv; r.w *= inv;
        float* outp = out + (((size_t)b * Hc + h) * SPLc + s) * LVc + 4 * lane;
        *reinterpret_cast<float4*>(outp) = r;
        if (lane == 0) {
            out[(size_t)Bc * Hc * SPLc * LVc + ((size_t)b * Hc + h) * SPLc + s] =
                M_FIX + logf(es);
        }
    }
}

} // anonymous namespace

extern "C" void kernel_launch(void* const* d_in, const int* in_sizes, int n_in,
                              void* d_out, int out_size, void* d_ws, size_t ws_size,
                              hipStream_t stream) {
    const float* q       = (const float*)d_in[0];
    const float* kbuf    = (const float*)d_in[1];
    const float* vbuf    = (const float*)d_in[2];
    const int*   indptr  = (const int*)d_in[3];
    const int*   indices = (const int*)d_in[4];
    const int*   nspl    = (const int*)d_in[5];
    float* outp = (float*)d_out;

    dim3 grid(Bc * Hc * SPLc);   // 1024 blocks: one per (b, h, split)
    dim3 block(256);
    hipLaunchKernelGGL(decode_attn, grid, block, 0, stream,
                       q, kbuf, vbuf, indptr, indices, nspl, outp);
}